// Round 16
// baseline (788.159 us; speedup 1.0000x reference)
//
#include <hip/hip_runtime.h>

// LightGCN 3-layer propagation — R15: R14 with the sr-buffer size fix.
//
// R14 post-mortem: CRASH — sr is indexed by slop-bucket positions (up to
// NB*BCAP = 5.6M) but was sized NE = 5.0M -> overflow clobbered offs2/dinv.
// Fix: SRB = NB*BCAP*4 (as in R13). Theory unchanged: mirror-based epilogue
// replaces prop3's 537MB fp32 x0..x2 re-read with 269MB bf16 mirror reads
// (x_l = y_l / dinv; deg-0 nodes read layer-0 fp32, x1..x3 = 0).

static constexpr int NUSERS = 500000;
static constexpr int NITEMS = 200000;
static constexpr int NNODES = 700000;   // NUSERS + NITEMS
static constexpr int NE     = 5000000;
static constexpr int NB     = (NNODES + 1023) / 1024;   // 684 buckets
static constexpr int BCAP   = 8192;                     // bucket region capacity
static constexpr int CH     = 4096;                     // edges per k_bpart block

typedef float f4 __attribute__((ext_vector_type(4)));   // native vec for nt ops

// round-to-nearest-even fp32 -> bf16 (as uint16 in low bits)
__device__ inline unsigned bf16rne(float f) {
    unsigned u = __float_as_uint(f);
    return (u + 0x7FFFu + ((u >> 16) & 1u)) >> 16;
}
__device__ inline unsigned packbf(float lo, float hi) {
    return bf16rne(lo) | (bf16rne(hi) << 16);
}
__device__ inline void acc8(float4& A, float4& B, uint4 q) {
    A.x += __uint_as_float(q.x << 16); A.y += __uint_as_float(q.x & 0xFFFF0000u);
    A.z += __uint_as_float(q.y << 16); A.w += __uint_as_float(q.y & 0xFFFF0000u);
    B.x += __uint_as_float(q.z << 16); B.y += __uint_as_float(q.z & 0xFFFF0000u);
    B.z += __uint_as_float(q.w << 16); B.w += __uint_as_float(q.w & 0xFFFF0000u);
}
__device__ inline void unpack8(uint4 q, f4& A, f4& B) {
    A = (f4){__uint_as_float(q.x << 16), __uint_as_float(q.x & 0xFFFF0000u),
             __uint_as_float(q.y << 16), __uint_as_float(q.y & 0xFFFF0000u)};
    B = (f4){__uint_as_float(q.z << 16), __uint_as_float(q.z & 0xFFFF0000u),
             __uint_as_float(q.w << 16), __uint_as_float(q.w & 0xFFFF0000u)};
}

// --- partition edges into slop bucket regions (packed (c_local<<20)|r) -------
__global__ void k_bpart(const int* __restrict__ row, const int* __restrict__ col,
                        int* __restrict__ bfill, unsigned* __restrict__ pairs) {
    __shared__ unsigned pe[CH];      // packed (c_local<<20)|r
    __shared__ unsigned short pb[CH];// bucket id
    __shared__ int lh[NB];
    __shared__ int lbase[NB];
    int t = threadIdx.x;
    for (int i = t; i < NB; i += 256) lh[i] = 0;
    __syncthreads();
    int base = blockIdx.x * CH;
    int cnt = min(CH, NE - base);
    for (int i = t; i < cnt; i += 256) {
        int c = col[base + i], r = row[base + i];
        int b = c >> 10;
        pe[i] = ((unsigned)(c & 1023) << 20) | (unsigned)r;
        pb[i] = (unsigned short)b;
        atomicAdd(&lh[b], 1);
    }
    __syncthreads();
    for (int b = t; b < NB; b += 256) {
        int v = lh[b];
        if (v) lbase[b] = atomicAdd(&bfill[b], v);
        lh[b] = 0;                                // re-zero for rank pass
    }
    __syncthreads();
    for (int i = t; i < cnt; i += 256) {
        int b = pb[i];
        int pos = lbase[b] + atomicAdd(&lh[b], 1);
        pairs[(size_t)b * BCAP + pos] = pe[i];
    }
}

// --- per-bucket counting sort: dinv/offs2 + sr placement ---------------------
__global__ void k_bsort(const unsigned* __restrict__ pairs, const int* __restrict__ bfill,
                        int* __restrict__ sr, float* __restrict__ dinv,
                        int2* __restrict__ offs2) {
    __shared__ int cnt[1024];
    __shared__ int cur[1024];
    __shared__ int part[256];
    int b = blockIdx.x;
    int t = threadIdx.x;
    int lo = b * BCAP;
    int hi = lo + bfill[b];
    int nbase = b << 10;
    for (int i = t; i < 1024; i += 256) cnt[i] = 0;
    __syncthreads();
    for (int k = lo + t; k < hi; k += 256)
        atomicAdd(&cnt[pairs[k] >> 20], 1);
    __syncthreads();
    int s0 = cnt[t * 4], s1 = cnt[t * 4 + 1], s2 = cnt[t * 4 + 2], s3 = cnt[t * 4 + 3];
    int tot = s0 + s1 + s2 + s3;
    part[t] = tot;
    __syncthreads();
    for (int off = 1; off < 256; off <<= 1) {
        int add = (t >= off) ? part[t - off] : 0;
        __syncthreads();
        part[t] += add;
        __syncthreads();
    }
    int pbase = part[t] - tot;                    // exclusive
    int e0 = pbase, e1 = pbase + s0, e2 = e1 + s1, e3 = e2 + s2;
    cur[t * 4] = e0; cur[t * 4 + 1] = e1; cur[t * 4 + 2] = e2; cur[t * 4 + 3] = e3;
    int n0 = nbase + t * 4;
    if (n0 + 0 < NNODES) { dinv[n0+0] = s0 ? rsqrtf((float)s0) : 0.f;
                           offs2[n0+0] = make_int2(lo + e0, lo + e0 + s0); }
    if (n0 + 1 < NNODES) { dinv[n0+1] = s1 ? rsqrtf((float)s1) : 0.f;
                           offs2[n0+1] = make_int2(lo + e1, lo + e1 + s1); }
    if (n0 + 2 < NNODES) { dinv[n0+2] = s2 ? rsqrtf((float)s2) : 0.f;
                           offs2[n0+2] = make_int2(lo + e2, lo + e2 + s2); }
    if (n0 + 3 < NNODES) { dinv[n0+3] = s3 ? rsqrtf((float)s3) : 0.f;
                           offs2[n0+3] = make_int2(lo + e3, lo + e3 + s3); }
    __syncthreads();
    for (int k = lo + t; k < hi; k += 256) {
        unsigned u = pairs[k];
        int pos = lo + atomicAdd(&cur[u >> 20], 1);
        sr[pos] = (int)(u & 0xFFFFFu);
    }
}

// --- init: layer-0 fp32 (nt) + prescaled bf16 mirror (full-grid pass) --------
__global__ void k_init(const float4* __restrict__ user, const float4* __restrict__ item,
                       float4* __restrict__ all_emb, const float* __restrict__ dinv,
                       uint4* __restrict__ xb0) {
    int tid = blockIdx.x * blockDim.x + threadIdx.x;
    if (tid >= NNODES * 8) return;
    int n    = tid >> 3;
    int lane = tid & 7;
    const float4* s = ((n < NUSERS) ? user + (size_t)n * 16
                                    : item + (size_t)(n - NUSERS) * 16) + lane * 2;
    float4 a = s[0], b = s[1];
    f4* dst = reinterpret_cast<f4*>(all_emb + (size_t)n * 64 + lane * 2);
    f4 av = {a.x, a.y, a.z, a.w};
    f4 bv = {b.x, b.y, b.z, b.w};
    __builtin_nontemporal_store(av, dst + 0);
    __builtin_nontemporal_store(bv, dst + 1);
    float dv = dinv[n];
    uint4 o;
    o.x = packbf(dv * a.x, dv * a.y); o.y = packbf(dv * a.z, dv * a.w);
    o.z = packbf(dv * b.x, dv * b.y); o.w = packbf(dv * b.z, dv * b.w);
    xb0[(size_t)n * 8 + lane] = o;
}

// --- propagate layer L -------------------------------------------------------
// EMODE 0: write bf16 mirror (L=1,2). EMODE 1: fp32 epilogue (R13 fallback).
// EMODE 2: mirror epilogue (reads ybA=y0, ybB=y1, xbp=y2).
template <int L, int EMODE>
__global__ void k_prop(const int2* __restrict__ offs2,
                       const int* __restrict__ sr, const float* __restrict__ dinv,
                       const uint4* __restrict__ xbp,
                       uint4* __restrict__ xbc,
                       const uint4* __restrict__ ybA, const uint4* __restrict__ ybB,
                       float4* __restrict__ all_emb,
                       float* __restrict__ out_users, float* __restrict__ out_items) {
    int tid = blockIdx.x * blockDim.x + threadIdx.x;
    if (tid >= NNODES * 8) return;
    int n    = tid >> 3;
    int lane = tid & 7;
    int2 be = offs2[n];
    int b = be.x, e = be.y;
    float4 accA = make_float4(0.f, 0.f, 0.f, 0.f);
    float4 accB = make_float4(0.f, 0.f, 0.f, 0.f);
    const uint4* src = xbp + lane;

    int k = b;
    for (; k + 4 <= e; k += 4) {
        int r0 = sr[k + 0], r1 = sr[k + 1], r2 = sr[k + 2], r3 = sr[k + 3];
        uint4 q0 = src[(size_t)r0 * 8];
        uint4 q1 = src[(size_t)r1 * 8];
        uint4 q2 = src[(size_t)r2 * 8];
        uint4 q3 = src[(size_t)r3 * 8];
        acc8(accA, accB, q0); acc8(accA, accB, q1);
        acc8(accA, accB, q2); acc8(accA, accB, q3);
    }
    for (; k < e; ++k) {
        uint4 q = src[(size_t)sr[k] * 8];
        acc8(accA, accB, q);
    }
    float dv = dinv[n];
    accA.x *= dv; accA.y *= dv; accA.z *= dv; accA.w *= dv;
    accB.x *= dv; accB.y *= dv; accB.z *= dv; accB.w *= dv;

    f4 aA = {accA.x, accA.y, accA.z, accA.w};
    f4 aB = {accB.x, accB.y, accB.z, accB.w};
    f4* dstn = reinterpret_cast<f4*>(all_emb + (size_t)n * 64 + L * 16 + lane * 2);
    __builtin_nontemporal_store(aA, dstn + 0);
    __builtin_nontemporal_store(aB, dstn + 1);

    if constexpr (EMODE == 0) {
        uint4 o;
        o.x = packbf(dv * accA.x, dv * accA.y);
        o.y = packbf(dv * accA.z, dv * accA.w);
        o.z = packbf(dv * accB.x, dv * accB.y);
        o.w = packbf(dv * accB.z, dv * accB.w);
        xbc[(size_t)n * 8 + lane] = o;
    } else {
        f4 ma, mb;
        if constexpr (EMODE == 1) {
            const f4* p = reinterpret_cast<const f4*>(all_emb + (size_t)n * 64 + lane * 2);
            f4 x0a = __builtin_nontemporal_load(p + 0);
            f4 x0b = __builtin_nontemporal_load(p + 1);
            f4 x1a = __builtin_nontemporal_load(p + 16);
            f4 x1b = __builtin_nontemporal_load(p + 17);
            f4 x2a = __builtin_nontemporal_load(p + 32);
            f4 x2b = __builtin_nontemporal_load(p + 33);
            ma = (x0a + x1a + x2a + aA) * 0.25f;
            mb = (x0b + x1b + x2b + aB) * 0.25f;
        } else {
            if (dv > 0.f) {
                float inv = 1.0f / dv;
                uint4 q0 = ybA[(size_t)n * 8 + lane];
                uint4 q1 = ybB[(size_t)n * 8 + lane];
                uint4 q2 = xbp[(size_t)n * 8 + lane];
                f4 a0, b0, a1, b1, a2, b2;
                unpack8(q0, a0, b0); unpack8(q1, a1, b1); unpack8(q2, a2, b2);
                ma = ((a0 + a1 + a2) * inv + aA) * 0.25f;
                mb = ((b0 + b1 + b2) * inv + aB) * 0.25f;
            } else {
                // deg-0: x1=x2=x3=0; x0 from all_emb layer 0 (rare)
                const f4* p = reinterpret_cast<const f4*>(all_emb + (size_t)n * 64 + lane * 2);
                ma = p[0] * 0.25f;
                mb = p[1] * 0.25f;
            }
        }
        if (n < NUSERS) {
            f4* ou = reinterpret_cast<f4*>(out_users + (size_t)n * 64 + lane * 8);
            __builtin_nontemporal_store(ma, ou + 0);
            __builtin_nontemporal_store(mb, ou + 1);
        }
        if (n >= NITEMS) {
            f4* oi = reinterpret_cast<f4*>(out_items + (size_t)(n - NITEMS) * 64 + lane * 8);
            __builtin_nontemporal_store(ma, oi + 0);
            __builtin_nontemporal_store(mb, oi + 1);
        }
    }
}

extern "C" void kernel_launch(void* const* d_in, const int* in_sizes, int n_in,
                              void* d_out, int out_size, void* d_ws, size_t ws_size,
                              hipStream_t stream) {
    const float* user  = (const float*)d_in[0];
    const float* item  = (const float*)d_in[1];
    const int*   edges = (const int*)d_in[2];
    const int*   row = edges;            // edge_index[0]
    const int*   col = edges + NE;       // edge_index[1]

    float* out       = (float*)d_out;
    float* out_users = out;
    float* out_items = out + (size_t)NUSERS * 64;
    float* all_emb   = out + (size_t)NUSERS * 64 * 2;   // [700000][4][64]

    const size_t MIR   = (size_t)NNODES * 128;          // 89.6 MB bf16 mirror
    const size_t SRB   = (size_t)NB * BCAP * 4;         // 22.4 MB (slop-indexed!)
    const size_t PAIRS = (size_t)NB * BCAP * 4;         // 22.4 MB
    const size_t OFF2  = (size_t)NNODES * 8;
    const size_t DINB  = (size_t)NNODES * 4;
    const size_t BFB   = (size_t)NB * 4;

    // 3-mirror layout: [xbB][xbC][sr][offs2][dinv][bfill][xbA ∪ pairs]
    const size_t need3 = MIR * 2 + SRB + OFF2 + DINB + BFB + (MIR > PAIRS ? MIR : PAIRS);
    const bool mir3 = (ws_size >= need3);

    char* ws = (char*)d_ws;
    uint4*    xbB; uint4* xbC; uint4* xbA;
    unsigned* pairs;
    int*      sr;  int2* offs2; float* dinv; int* bfill;

    if (mir3) {
        xbB   = (uint4*)ws;      ws += MIR;
        xbC   = (uint4*)ws;      ws += MIR;
        sr    = (int*)ws;        ws += SRB;
        offs2 = (int2*)ws;       ws += OFF2;
        dinv  = (float*)ws;      ws += DINB;
        bfill = (int*)ws;        ws += BFB;
        xbA   = (uint4*)ws;                      // union region
        pairs = (unsigned*)ws;                   // dead after k_bsort; k_init overwrites
    } else {
        // R13 fallback: 2 mirrors, fp32 epilogue
        xbA   = (uint4*)ws;      ws += MIR;      // xb0
        xbB   = (uint4*)ws;      ws += MIR;      // xb1
        xbC   = xbA;                             // prop2 dst ping-pongs back
        pairs = (unsigned*)ws;   ws += PAIRS;
        sr    = (int*)ws;        ws += SRB;
        offs2 = (int2*)ws;       ws += OFF2;
        dinv  = (float*)ws;      ws += DINB;
        bfill = (int*)ws;        ws += BFB;
    }

    const int B = 256;
    const int prop_grid = (NNODES * 8 + B - 1) / B;

    (void)hipMemsetAsync(bfill, 0, BFB, stream);
    k_bpart<<<(NE + CH - 1) / CH, 256, 0, stream>>>(row, col, bfill, pairs);
    k_bsort<<<NB, 256, 0, stream>>>(pairs, bfill, sr, dinv, offs2);
    k_init <<<prop_grid, B, 0, stream>>>(
        (const float4*)user, (const float4*)item, (float4*)all_emb, dinv, xbA);

    k_prop<1, 0><<<prop_grid, B, 0, stream>>>(offs2, sr, dinv, xbA, xbB, nullptr, nullptr,
                                              (float4*)all_emb, nullptr, nullptr);
    k_prop<2, 0><<<prop_grid, B, 0, stream>>>(offs2, sr, dinv, xbB, xbC, nullptr, nullptr,
                                              (float4*)all_emb, nullptr, nullptr);
    if (mir3) {
        k_prop<3, 2><<<prop_grid, B, 0, stream>>>(offs2, sr, dinv, xbC, nullptr, xbA, xbB,
                                                  (float4*)all_emb, out_users, out_items);
    } else {
        k_prop<3, 1><<<prop_grid, B, 0, stream>>>(offs2, sr, dinv, xbC, nullptr, nullptr, nullptr,
                                                  (float4*)all_emb, out_users, out_items);
    }
}

// Round 17
// 713.060 us; speedup vs baseline: 1.1053x; 1.1053x over previous
//
#include <hip/hip_runtime.h>

// LightGCN 3-layer propagation — R16: 2-mirror epilogue-from-inputs.
//
// R15 post-mortem: 3-mirror design flawed — either ws guard fell back (and
// co-compiled templates perturbed codegen, +51us) or 268MB of live mirrors
// blew L3. R16: epilogue x0 comes from the INPUT arrays (user/item, nt fp32),
// x1=y1/dinv from xbB, x2=y2/dinv from xbA (L3-hot gather source). Live
// mirror set stays 179MB; layout byte-identical to proven R13.

static constexpr int NUSERS = 500000;
static constexpr int NITEMS = 200000;
static constexpr int NNODES = 700000;   // NUSERS + NITEMS
static constexpr int NE     = 5000000;
static constexpr int NB     = (NNODES + 1023) / 1024;   // 684 buckets
static constexpr int BCAP   = 8192;                     // bucket region capacity
static constexpr int CH     = 4096;                     // edges per k_bpart block

typedef float f4 __attribute__((ext_vector_type(4)));   // native vec for nt ops

// round-to-nearest-even fp32 -> bf16 (as uint16 in low bits)
__device__ inline unsigned bf16rne(float f) {
    unsigned u = __float_as_uint(f);
    return (u + 0x7FFFu + ((u >> 16) & 1u)) >> 16;
}
__device__ inline unsigned packbf(float lo, float hi) {
    return bf16rne(lo) | (bf16rne(hi) << 16);
}
__device__ inline void acc8(float4& A, float4& B, uint4 q) {
    A.x += __uint_as_float(q.x << 16); A.y += __uint_as_float(q.x & 0xFFFF0000u);
    A.z += __uint_as_float(q.y << 16); A.w += __uint_as_float(q.y & 0xFFFF0000u);
    B.x += __uint_as_float(q.z << 16); B.y += __uint_as_float(q.z & 0xFFFF0000u);
    B.z += __uint_as_float(q.w << 16); B.w += __uint_as_float(q.w & 0xFFFF0000u);
}
__device__ inline void unpack8(uint4 q, f4& A, f4& B) {
    A = (f4){__uint_as_float(q.x << 16), __uint_as_float(q.x & 0xFFFF0000u),
             __uint_as_float(q.y << 16), __uint_as_float(q.y & 0xFFFF0000u)};
    B = (f4){__uint_as_float(q.z << 16), __uint_as_float(q.z & 0xFFFF0000u),
             __uint_as_float(q.w << 16), __uint_as_float(q.w & 0xFFFF0000u)};
}

// --- partition edges into slop bucket regions (packed (c_local<<20)|r) -------
__global__ void k_bpart(const int* __restrict__ row, const int* __restrict__ col,
                        int* __restrict__ bfill, unsigned* __restrict__ pairs) {
    __shared__ unsigned pe[CH];      // packed (c_local<<20)|r
    __shared__ unsigned short pb[CH];// bucket id
    __shared__ int lh[NB];
    __shared__ int lbase[NB];
    int t = threadIdx.x;
    for (int i = t; i < NB; i += 256) lh[i] = 0;
    __syncthreads();
    int base = blockIdx.x * CH;
    int cnt = min(CH, NE - base);
    for (int i = t; i < cnt; i += 256) {
        int c = col[base + i], r = row[base + i];
        int b = c >> 10;
        pe[i] = ((unsigned)(c & 1023) << 20) | (unsigned)r;
        pb[i] = (unsigned short)b;
        atomicAdd(&lh[b], 1);
    }
    __syncthreads();
    for (int b = t; b < NB; b += 256) {
        int v = lh[b];
        if (v) lbase[b] = atomicAdd(&bfill[b], v);
        lh[b] = 0;                                // re-zero for rank pass
    }
    __syncthreads();
    for (int i = t; i < cnt; i += 256) {
        int b = pb[i];
        int pos = lbase[b] + atomicAdd(&lh[b], 1);
        pairs[(size_t)b * BCAP + pos] = pe[i];
    }
}

// --- per-bucket counting sort: dinv/offs2 + sr placement ---------------------
__global__ void k_bsort(const unsigned* __restrict__ pairs, const int* __restrict__ bfill,
                        int* __restrict__ sr, float* __restrict__ dinv,
                        int2* __restrict__ offs2) {
    __shared__ int cnt[1024];
    __shared__ int cur[1024];
    __shared__ int part[256];
    int b = blockIdx.x;
    int t = threadIdx.x;
    int lo = b * BCAP;
    int hi = lo + bfill[b];
    int nbase = b << 10;
    for (int i = t; i < 1024; i += 256) cnt[i] = 0;
    __syncthreads();
    for (int k = lo + t; k < hi; k += 256)
        atomicAdd(&cnt[pairs[k] >> 20], 1);
    __syncthreads();
    int s0 = cnt[t * 4], s1 = cnt[t * 4 + 1], s2 = cnt[t * 4 + 2], s3 = cnt[t * 4 + 3];
    int tot = s0 + s1 + s2 + s3;
    part[t] = tot;
    __syncthreads();
    for (int off = 1; off < 256; off <<= 1) {
        int add = (t >= off) ? part[t - off] : 0;
        __syncthreads();
        part[t] += add;
        __syncthreads();
    }
    int pbase = part[t] - tot;                    // exclusive
    int e0 = pbase, e1 = pbase + s0, e2 = e1 + s1, e3 = e2 + s2;
    cur[t * 4] = e0; cur[t * 4 + 1] = e1; cur[t * 4 + 2] = e2; cur[t * 4 + 3] = e3;
    int n0 = nbase + t * 4;
    if (n0 + 0 < NNODES) { dinv[n0+0] = s0 ? rsqrtf((float)s0) : 0.f;
                           offs2[n0+0] = make_int2(lo + e0, lo + e0 + s0); }
    if (n0 + 1 < NNODES) { dinv[n0+1] = s1 ? rsqrtf((float)s1) : 0.f;
                           offs2[n0+1] = make_int2(lo + e1, lo + e1 + s1); }
    if (n0 + 2 < NNODES) { dinv[n0+2] = s2 ? rsqrtf((float)s2) : 0.f;
                           offs2[n0+2] = make_int2(lo + e2, lo + e2 + s2); }
    if (n0 + 3 < NNODES) { dinv[n0+3] = s3 ? rsqrtf((float)s3) : 0.f;
                           offs2[n0+3] = make_int2(lo + e3, lo + e3 + s3); }
    __syncthreads();
    for (int k = lo + t; k < hi; k += 256) {
        unsigned u = pairs[k];
        int pos = lo + atomicAdd(&cur[u >> 20], 1);
        sr[pos] = (int)(u & 0xFFFFFu);
    }
}

// --- init: layer-0 fp32 (nt) + prescaled bf16 mirror (full-grid pass) --------
__global__ void k_init(const float4* __restrict__ user, const float4* __restrict__ item,
                       float4* __restrict__ all_emb, const float* __restrict__ dinv,
                       uint4* __restrict__ xb0) {
    int tid = blockIdx.x * blockDim.x + threadIdx.x;
    if (tid >= NNODES * 8) return;
    int n    = tid >> 3;
    int lane = tid & 7;
    const float4* s = ((n < NUSERS) ? user + (size_t)n * 16
                                    : item + (size_t)(n - NUSERS) * 16) + lane * 2;
    float4 a = s[0], b = s[1];
    f4* dst = reinterpret_cast<f4*>(all_emb + (size_t)n * 64 + lane * 2);
    f4 av = {a.x, a.y, a.z, a.w};
    f4 bv = {b.x, b.y, b.z, b.w};
    __builtin_nontemporal_store(av, dst + 0);
    __builtin_nontemporal_store(bv, dst + 1);
    float dv = dinv[n];
    uint4 o;
    o.x = packbf(dv * a.x, dv * a.y); o.y = packbf(dv * a.z, dv * a.w);
    o.z = packbf(dv * b.x, dv * b.y); o.w = packbf(dv * b.z, dv * b.w);
    xb0[(size_t)n * 8 + lane] = o;
}

// --- propagate layer L -------------------------------------------------------
// FUSE_OUT=false: write bf16 mirror (L=1,2).
// FUSE_OUT=true (L=3): epilogue mean from inputs (x0) + mirrors (x1,x2) + acc.
template <int L, bool FUSE_OUT>
__global__ void k_prop(const int2* __restrict__ offs2,
                       const int* __restrict__ sr, const float* __restrict__ dinv,
                       const uint4* __restrict__ xbp,   // src mirror y_{L-1}
                       uint4* __restrict__ xbc,         // dst mirror y_L (L<3)
                       const uint4* __restrict__ yb1,   // y1 mirror (L==3)
                       const float4* __restrict__ user, const float4* __restrict__ item,
                       float4* __restrict__ all_emb,
                       float* __restrict__ out_users, float* __restrict__ out_items) {
    int tid = blockIdx.x * blockDim.x + threadIdx.x;
    if (tid >= NNODES * 8) return;
    int n    = tid >> 3;
    int lane = tid & 7;
    int2 be = offs2[n];
    int b = be.x, e = be.y;
    float4 accA = make_float4(0.f, 0.f, 0.f, 0.f);
    float4 accB = make_float4(0.f, 0.f, 0.f, 0.f);
    const uint4* src = xbp + lane;

    int k = b;
    for (; k + 4 <= e; k += 4) {
        int r0 = sr[k + 0], r1 = sr[k + 1], r2 = sr[k + 2], r3 = sr[k + 3];
        uint4 q0 = src[(size_t)r0 * 8];
        uint4 q1 = src[(size_t)r1 * 8];
        uint4 q2 = src[(size_t)r2 * 8];
        uint4 q3 = src[(size_t)r3 * 8];
        acc8(accA, accB, q0); acc8(accA, accB, q1);
        acc8(accA, accB, q2); acc8(accA, accB, q3);
    }
    for (; k < e; ++k) {
        uint4 q = src[(size_t)sr[k] * 8];
        acc8(accA, accB, q);
    }
    float dv = dinv[n];
    accA.x *= dv; accA.y *= dv; accA.z *= dv; accA.w *= dv;
    accB.x *= dv; accB.y *= dv; accB.z *= dv; accB.w *= dv;

    f4 aA = {accA.x, accA.y, accA.z, accA.w};
    f4 aB = {accB.x, accB.y, accB.z, accB.w};
    f4* dstn = reinterpret_cast<f4*>(all_emb + (size_t)n * 64 + L * 16 + lane * 2);
    __builtin_nontemporal_store(aA, dstn + 0);
    __builtin_nontemporal_store(aB, dstn + 1);

    if constexpr (!FUSE_OUT) {
        uint4 o;
        o.x = packbf(dv * accA.x, dv * accA.y);
        o.y = packbf(dv * accA.z, dv * accA.w);
        o.z = packbf(dv * accB.x, dv * accB.y);
        o.w = packbf(dv * accB.z, dv * accB.w);
        xbc[(size_t)n * 8 + lane] = o;
    } else {
        // x0 from inputs (streaming, nt)
        const f4* s = reinterpret_cast<const f4*>(
            ((n < NUSERS) ? user + (size_t)n * 16
                          : item + (size_t)(n - NUSERS) * 16) + lane * 2);
        f4 x0a = __builtin_nontemporal_load(s + 0);
        f4 x0b = __builtin_nontemporal_load(s + 1);
        f4 ma, mb;
        if (dv > 0.f) {
            float inv = 1.0f / dv;
            uint4 q1 = yb1[(size_t)n * 8 + lane];    // y1
            uint4 q2 = xbp[(size_t)n * 8 + lane];    // y2 (gather source, L3-hot)
            f4 a1, b1, a2, b2;
            unpack8(q1, a1, b1); unpack8(q2, a2, b2);
            ma = (x0a + (a1 + a2) * inv + aA) * 0.25f;
            mb = (x0b + (b1 + b2) * inv + aB) * 0.25f;
        } else {
            // deg-0: x1=x2=x3=0
            ma = x0a * 0.25f;
            mb = x0b * 0.25f;
        }
        if (n < NUSERS) {
            f4* ou = reinterpret_cast<f4*>(out_users + (size_t)n * 64 + lane * 8);
            __builtin_nontemporal_store(ma, ou + 0);
            __builtin_nontemporal_store(mb, ou + 1);
        }
        if (n >= NITEMS) {
            f4* oi = reinterpret_cast<f4*>(out_items + (size_t)(n - NITEMS) * 64 + lane * 8);
            __builtin_nontemporal_store(ma, oi + 0);
            __builtin_nontemporal_store(mb, oi + 1);
        }
    }
}

extern "C" void kernel_launch(void* const* d_in, const int* in_sizes, int n_in,
                              void* d_out, int out_size, void* d_ws, size_t ws_size,
                              hipStream_t stream) {
    const float* user  = (const float*)d_in[0];
    const float* item  = (const float*)d_in[1];
    const int*   edges = (const int*)d_in[2];
    const int*   row = edges;            // edge_index[0]
    const int*   col = edges + NE;       // edge_index[1]

    float* out       = (float*)d_out;
    float* out_users = out;
    float* out_items = out + (size_t)NUSERS * 64;
    float* all_emb   = out + (size_t)NUSERS * 64 * 2;   // [700000][4][64]

    // workspace carve — byte-identical to R13 (~233 MB, proven)
    char* ws = (char*)d_ws;
    uint4*    xbA   = (uint4*)ws;                     ws += (size_t)NNODES * 128;  // y0 -> y2
    uint4*    xbB   = (uint4*)ws;                     ws += (size_t)NNODES * 128;  // y1
    unsigned* pairs = (unsigned*)ws;                  ws += (size_t)NB * BCAP * 4;
    int*      sr    = (int*)ws;                       ws += (size_t)NB * BCAP * 4;
    int2*     offs2 = (int2*)ws;                      ws += (size_t)NNODES * 8;
    float*    dinv  = (float*)ws;                     ws += (size_t)NNODES * 4;
    int*      bfill = (int*)ws;                       ws += (size_t)NB * 4;

    const int B = 256;
    const int prop_grid = (NNODES * 8 + B - 1) / B;

    (void)hipMemsetAsync(bfill, 0, (size_t)NB * sizeof(int), stream);
    k_bpart<<<(NE + CH - 1) / CH, 256, 0, stream>>>(row, col, bfill, pairs);
    k_bsort<<<NB, 256, 0, stream>>>(pairs, bfill, sr, dinv, offs2);
    k_init <<<prop_grid, B, 0, stream>>>(
        (const float4*)user, (const float4*)item, (float4*)all_emb, dinv, xbA);

    k_prop<1, false><<<prop_grid, B, 0, stream>>>(offs2, sr, dinv, xbA, xbB, nullptr,
                                                  nullptr, nullptr,
                                                  (float4*)all_emb, nullptr, nullptr);
    k_prop<2, false><<<prop_grid, B, 0, stream>>>(offs2, sr, dinv, xbB, xbA, nullptr,
                                                  nullptr, nullptr,
                                                  (float4*)all_emb, nullptr, nullptr);
    k_prop<3, true> <<<prop_grid, B, 0, stream>>>(offs2, sr, dinv, xbA, nullptr, xbB,
                                                  (const float4*)user, (const float4*)item,
                                                  (float4*)all_emb, out_users, out_items);
}